// Round 7
// baseline (240.198 us; speedup 1.0000x reference)
//
#include <hip/hip_runtime.h>
#include <math.h>

#define IMG_H 1080
#define IMG_W 1920
#define NFLOW 5
#define HW (IMG_H * IMG_W)

#define TILE_W 64
#define TILE_H 32
#define HALO 24
#define REG_W (TILE_W + 2 * HALO)   // 112
#define REG_H (TILE_H + 2 * HALO)   // 80
#define THREADS 512
#define ITERS ((TILE_W * TILE_H) / THREADS)     // 4 (8 rows per iter)
#define GRID_X (IMG_W / TILE_W)                 // 30
#define GRID_Y ((IMG_H + TILE_H - 1) / TILE_H)  // 34
#define NBLOCKS (GRID_X * GRID_Y)               // 1020

__device__ __forceinline__ unsigned pack3(float a, float b, float c) {
    const unsigned c0 = (unsigned)(int)(a + 0.5f);
    const unsigned c1 = (unsigned)(int)(b + 0.5f);
    const unsigned c2 = (unsigned)(int)(c + 0.5f);
    return c0 | (c1 << 8) | (c2 << 16);
}

// One fused kernel: vector-stage+pack f1 tile (u8 RGB in u32), software-
// pipelined warped-SSE for 5 flows, block reduce + atomics, last-block finalize.
__global__ __launch_bounds__(THREADS, 8) void psnr_mega_kernel(
    const float2* __restrict__ flow,   // [N][H][W] float2
    const float* __restrict__ f1,      // [3][H][W]
    const float* __restrict__ f2,      // [3][H][W]
    float* __restrict__ sums,          // [5] zeroed
    unsigned int* __restrict__ counter,// [1] zeroed
    float* __restrict__ out)           // [1]
{
    __shared__ __align__(16) unsigned int tile[REG_H * REG_W];  // 35840 B
    __shared__ float sacc[NFLOW][THREADS / 64];

    // --- bijective XCD-chunked swizzle (1020 = 8*127 + 4) ---
    const int wg = blockIdx.x;
    const int xcd = wg & 7;
    const int idx = wg >> 3;
    const int q = NBLOCKS >> 3;        // 127
    const int rr = NBLOCKS & 7;        // 4
    const int wgid = (xcd < rr ? xcd * (q + 1) : rr * (q + 1) + (xcd - rr) * q) + idx;
    const int tyb = wgid / GRID_X;
    const int txb = wgid - tyb * GRID_X;

    const int tx0 = txb * TILE_W;
    const int ty0 = tyb * TILE_H;
    const int bx = tx0 - HALO;
    const int by = ty0 - HALO;
    const int tid = threadIdx.x;

    // --- stage frame1 halo region as packed u8 RGB, 4 texels per iteration.
    // Out-of-image texels staged as 0 (zeros padding: weight*0).
    for (int qi = tid; qi < (REG_H * REG_W) / 4; qi += THREADS) {
        const int ry = qi / (REG_W / 4);
        const int rxq = qi - ry * (REG_W / 4);
        const int rx = rxq * 4;
        const int gy = by + ry;
        const int gx0 = bx + rx;
        uint4 ov;
        if ((unsigned)gy < (unsigned)IMG_H) {
            if (gx0 >= 0 && gx0 + 3 < IMG_W) {
                const int gp = gy * IMG_W + gx0;
                const float4 c0 = *(const float4*)(f1 + gp);
                const float4 c1 = *(const float4*)(f1 + HW + gp);
                const float4 c2 = *(const float4*)(f1 + 2 * HW + gp);
                ov.x = pack3(c0.x, c1.x, c2.x);
                ov.y = pack3(c0.y, c1.y, c2.y);
                ov.z = pack3(c0.z, c1.z, c2.z);
                ov.w = pack3(c0.w, c1.w, c2.w);
            } else {
                unsigned vv[4];
#pragma unroll
                for (int j = 0; j < 4; ++j) {
                    const int gx = gx0 + j;
                    unsigned v = 0u;
                    if ((unsigned)gx < (unsigned)IMG_W) {
                        const int gp = gy * IMG_W + gx;
                        v = pack3(f1[gp], f1[HW + gp], f1[2 * HW + gp]);
                    }
                    vv[j] = v;
                }
                ov.x = vv[0]; ov.y = vv[1]; ov.z = vv[2]; ov.w = vv[3];
            }
        } else {
            ov.x = 0u; ov.y = 0u; ov.z = 0u; ov.w = 0u;
        }
        *(uint4*)&tile[ry * REG_W + rx] = ov;   // ds_write_b128, 16B-aligned
    }
    __syncthreads();

    float acc[NFLOW];
#pragma unroll
    for (int n = 0; n < NFLOW; ++n) acc[n] = 0.0f;

    const int lx = tid & 63;          // column within tile row
    const int rowoff = tid >> 6;      // 0..7 within each 8-row group
    const int gx = tx0 + lx;

    // per-flow processing (n static via unroll; fl in registers)
    auto proc = [&](int n, float2 fl, int gy, float r0, float r1, float r2) {
        // all 4 taps provably inside staged rect iff flow within [-HALO, HALO)
        const bool ok = (fl.x >= -(float)HALO) && (fl.x < (float)HALO) &&
                        (fl.y >= -(float)HALO) && (fl.y < (float)HALO);

        const float px = (float)gx + fl.x;
        const float py = (float)gy + fl.y;
        const float x0f = floorf(px);
        const float y0f = floorf(py);
        const float wx1 = px - x0f;
        const float wy1 = py - y0f;
        const float wx0 = 1.0f - wx1;
        const float wy0 = 1.0f - wy1;

        const bool vx0 = (x0f >= 0.0f) && (x0f <= (float)(IMG_W - 1));
        const bool vx1 = (x0f >= -1.0f) && (x0f <= (float)(IMG_W - 2));
        const bool vy0 = (y0f >= 0.0f) && (y0f <= (float)(IMG_H - 1));
        const bool vy1 = (y0f >= -1.0f) && (y0f <= (float)(IMG_H - 2));

        const float w00 = (vx0 && vy0) ? (wx0 * wy0) : 0.0f;
        const float w10 = (vx1 && vy0) ? (wx1 * wy0) : 0.0f;
        const float w01 = (vx0 && vy1) ? (wx0 * wy1) : 0.0f;
        const float w11 = (vx1 && vy1) ? (wx1 * wy1) : 0.0f;

        float e0, e1, e2;
        if (ok) {
            const int x0i = (int)x0f;
            const int y0i = (int)y0f;
            const int ri = (y0i - by) * REG_W + (x0i - bx);
            const unsigned v00 = tile[ri];
            const unsigned v10 = tile[ri + 1];
            const unsigned v01 = tile[ri + REG_W];
            const unsigned v11 = tile[ri + REG_W + 1];

            e0 = (float)(v00 & 255u) * w00 + (float)(v10 & 255u) * w10 +
                 (float)(v01 & 255u) * w01 + (float)(v11 & 255u) * w11;
            e1 = (float)((v00 >> 8) & 255u) * w00 + (float)((v10 >> 8) & 255u) * w10 +
                 (float)((v01 >> 8) & 255u) * w01 + (float)((v11 >> 8) & 255u) * w11;
            e2 = (float)((v00 >> 16) & 255u) * w00 + (float)((v10 >> 16) & 255u) * w10 +
                 (float)((v01 >> 16) & 255u) * w01 + (float)((v11 >> 16) & 255u) * w11;
        } else {
            // rare outlier (P ~ 3e-6): exact f32 gather with clamping
            const int x0i = (int)fminf(fmaxf(x0f, 0.0f), (float)(IMG_W - 1));
            const int x1i = (int)fminf(fmaxf(x0f + 1.0f, 0.0f), (float)(IMG_W - 1));
            const int y0i = (int)fminf(fmaxf(y0f, 0.0f), (float)(IMG_H - 1));
            const int y1i = (int)fminf(fmaxf(y0f + 1.0f, 0.0f), (float)(IMG_H - 1));
            const int i00 = y0i * IMG_W + x0i;
            const int i10 = y0i * IMG_W + x1i;
            const int i01 = y1i * IMG_W + x0i;
            const int i11 = y1i * IMG_W + x1i;
            e0 = f1[i00] * w00 + f1[i10] * w10 + f1[i01] * w01 + f1[i11] * w11;
            e1 = f1[HW + i00] * w00 + f1[HW + i10] * w10 +
                 f1[HW + i01] * w01 + f1[HW + i11] * w11;
            e2 = f1[2 * HW + i00] * w00 + f1[2 * HW + i10] * w10 +
                 f1[2 * HW + i01] * w01 + f1[2 * HW + i11] * w11;
        }

        const float d0 = r0 - truncf(e0);
        const float d1 = r1 - truncf(e1);
        const float d2 = r2 - truncf(e2);
        acc[n] += d0 * d0 + d1 * d1 + d2 * d2;
    };

    // --- software-pipelined main loop: prefetch it+1 while computing it.
    // Row-group validity is uniform per iteration (1080 - ty0 ≡ 0 mod 8).
    float2 cfl0, cfl1, cfl2, cfl3, cfl4;
    float cr0, cr1, cr2;
    {
        const int gy = ty0 + rowoff;             // iter 0 always valid
        const int p = gy * IMG_W + gx;
        cfl0 = flow[p];
        cfl1 = flow[HW + p];
        cfl2 = flow[2 * HW + p];
        cfl3 = flow[3 * HW + p];
        cfl4 = flow[4 * HW + p];
        cr0 = f2[p];
        cr1 = f2[HW + p];
        cr2 = f2[2 * HW + p];
    }

#pragma unroll
    for (int it = 0; it < ITERS; ++it) {
        const bool curv = (ty0 + it * 8) < IMG_H;

        float2 nfl0 = {0.f, 0.f}, nfl1 = {0.f, 0.f}, nfl2 = {0.f, 0.f},
               nfl3 = {0.f, 0.f}, nfl4 = {0.f, 0.f};
        float nr0 = 0.f, nr1 = 0.f, nr2 = 0.f;
        if (it + 1 < ITERS && (ty0 + (it + 1) * 8) < IMG_H) {
            const int gy = ty0 + (it + 1) * 8 + rowoff;
            const int p = gy * IMG_W + gx;
            nfl0 = flow[p];
            nfl1 = flow[HW + p];
            nfl2 = flow[2 * HW + p];
            nfl3 = flow[3 * HW + p];
            nfl4 = flow[4 * HW + p];
            nr0 = f2[p];
            nr1 = f2[HW + p];
            nr2 = f2[2 * HW + p];
        }

        if (curv) {
            const int gy = ty0 + it * 8 + rowoff;
            proc(0, cfl0, gy, cr0, cr1, cr2);
            proc(1, cfl1, gy, cr0, cr1, cr2);
            proc(2, cfl2, gy, cr0, cr1, cr2);
            proc(3, cfl3, gy, cr0, cr1, cr2);
            proc(4, cfl4, gy, cr0, cr1, cr2);
        }

        cfl0 = nfl0; cfl1 = nfl1; cfl2 = nfl2; cfl3 = nfl3; cfl4 = nfl4;
        cr0 = nr0; cr1 = nr1; cr2 = nr2;
    }

    // --- wave64 reduce, cross-wave LDS reduce, one atomic per block per flow
#pragma unroll
    for (int n = 0; n < NFLOW; ++n) {
#pragma unroll
        for (int off = 32; off > 0; off >>= 1)
            acc[n] += __shfl_down(acc[n], off, 64);
    }
    const int lane = threadIdx.x & 63;
    const int wid = threadIdx.x >> 6;
    if (lane == 0) {
#pragma unroll
        for (int n = 0; n < NFLOW; ++n) sacc[n][wid] = acc[n];
    }
    __syncthreads();

    if (tid == 0) {
#pragma unroll
        for (int n = 0; n < NFLOW; ++n) {
            float s = 0.0f;
#pragma unroll
            for (int w = 0; w < THREADS / 64; ++w) s += sacc[n][w];
            atomicAdd(&sums[n], s);
        }

        // --- last-block finalize (device-scope counter handshake)
        __threadfence();
        if (atomicAdd(counter, 1u) == (unsigned)(NBLOCKS - 1)) {
            __threadfence();
            double aggr = 0.0;
            for (int n = 0; n < NFLOW; ++n) {
                const float sn = __hip_atomic_load(&sums[n], __ATOMIC_RELAXED,
                                                   __HIP_MEMORY_SCOPE_AGENT);
                const double mse = (double)sn / (3.0 * (double)HW);
                const double psnr = 10.0 * log10(255.0 * 255.0 / mse);
                double wgt = 1.0;
                for (int k = 0; k < NFLOW - n; ++k) wgt *= 0.85;
                aggr += psnr * wgt;
            }
            out[0] = (float)(-aggr);
        }
    }
}

extern "C" void kernel_launch(void* const* d_in, const int* in_sizes, int n_in,
                              void* d_out, int out_size, void* d_ws, size_t ws_size,
                              hipStream_t stream) {
    const float* flow = (const float*)d_in[0];  // [5,1080,1920,2]
    const float* f1   = (const float*)d_in[1];  // [3,1080,1920]
    const float* f2   = (const float*)d_in[2];  // [3,1080,1920]
    float* out = (float*)d_out;

    float* sums = (float*)d_ws;                               // 5 floats @ 0
    unsigned int* counter = (unsigned int*)((char*)d_ws + 32);// u32 @ 32

    hipMemsetAsync(d_ws, 0, 64, stream);
    psnr_mega_kernel<<<NBLOCKS, THREADS, 0, stream>>>(
        (const float2*)flow, f1, f2, sums, counter, out);
}